// Round 13
// baseline (5868.390 us; speedup 1.0000x reference)
//
#include <hip/hip_runtime.h>
#include <hip/hip_bf16.h>

#define TT 256
#define D 1024
#define BD (128 * 1024)
#define NWPL 85
#define NWG 256
#define NUSED 255
#define ROWLEN 1048
#define HSLOTS 264   // 8 zero-pad slots + 256 steps

typedef __attribute__((ext_vector_type(8))) short bf16x8;
typedef __attribute__((ext_vector_type(4))) float f32x4;

__device__ __forceinline__ unsigned short f2bf(float f) {
    __hip_bfloat16 h = __float2bfloat16(f);
    return *reinterpret_cast<unsigned short*>(&h);
}
__device__ __forceinline__ float bf2f(unsigned short u) {
    unsigned v = (unsigned)u << 16;
    return __builtin_bit_cast(float, v);
}

__global__ __launch_bounds__(256) void cvt_f32_bf16(const float* __restrict__ in,
                                                    unsigned short* __restrict__ out, int n) {
    int i = (blockIdx.x * 256 + threadIdx.x) * 8;
    if (i + 8 <= n) {
        float4 a = *(const float4*)(in + i);
        float4 b = *(const float4*)(in + i + 4);
        unsigned short t[8] = { f2bf(a.x), f2bf(a.y), f2bf(a.z), f2bf(a.w),
                                f2bf(b.x), f2bf(b.y), f2bf(b.z), f2bf(b.w) };
        *(uint4*)(out + i) = *(const uint4*)t;
    }
}

#define SB __builtin_amdgcn_sched_barrier(0)
#define AGLD(p) __hip_atomic_load((p), __ATOMIC_RELAXED, __HIP_MEMORY_SCOPE_AGENT)
#define AGST(p, v) __hip_atomic_store((p), (v), __ATOMIC_RELAXED, __HIP_MEMORY_SCOPE_AGENT)
#define GLSCD(dst, addr) asm volatile( \
    "global_load_dword %0, %1, off sc0 sc1" : "=v"(dst) : "v"(addr))
#define GLSC16(dst, base, IMM) asm volatile( \
    "global_load_dwordx4 %0, %1, off offset:%2 sc0 sc1" \
    : "=v"(dst) : "v"(base), "i"(IMM))
#define GLSCU(dst, addr) asm volatile( \
    "global_load_ushort %0, %1, off sc0 sc1" : "=v"(dst) : "v"(addr))
#define WAITV(N) { asm volatile("s_waitcnt vmcnt(%0)" :: "i"(N)); SB; }

// ============================================================================
// DEDUP kernel: write-once history buffers => all cross-WG A-reads are plain
// first-touch loads (no fences, no stale copies possible) => per-XCD L2
// dedups the A-broadcast. 4 waves x 32 rows, 3-deep compiler pipeline.
// ============================================================================
__global__ __launch_bounds__(256, 1) void dgru_dedup(
    const unsigned short* __restrict__ xbf,
    const float* __restrict__ Wih, const float* __restrict__ Whh,
    const float* __restrict__ bih, const float* __restrict__ bhh,
    unsigned short* __restrict__ hist,      // [3][HSLOTS][BD], slots 0..7 zeroed
    float* __restrict__ ring_f,             // [3][8][BD] (same-WG only)
    unsigned short* __restrict__ hin_hist,  // [2][TT][BD]
    float* __restrict__ out,
    unsigned* __restrict__ prog)
{
    __shared__ unsigned short wlds[78 * ROWLEN];

    const int grp = blockIdx.x & 7;
    const int p = 32 * grp + (blockIdx.x >> 3);  // XCD-packing heuristic (perf only)
    if (p >= NUSED) return;
    const int layer = p / NWPL;
    const int u     = p % NWPL;
    const int ncols = (u < 4) ? 13 : 12;
    const int c0    = u * 12 + (u < 4 ? u : 4);

    // ---- one-time: weight slice fp32 -> bf16 -> LDS (stationary)
    {
        const float* w0 = Wih + (size_t)layer * 3 * D * D;
        const float* w1 = Whh + (size_t)layer * 3 * D * D;
        const int nrows = 6 * ncols;
        for (int rid = 0; rid < nrows; ++rid) {
            int m   = rid / (3 * ncols);
            int rem = rid - m * 3 * ncols;
            int g   = rem / ncols;
            int c   = rem - g * ncols;
            const float* src = (m ? w1 : w0) + ((size_t)g * D + c0 + c) * D + threadIdx.x * 4;
            float4 v = *(const float4*)src;
            ushort4 o = { f2bf(v.x), f2bf(v.y), f2bf(v.z), f2bf(v.w) };
            *(ushort4*)&wlds[rid * ROWLEN + threadIdx.x * 4] = o;
        }
        __syncthreads();
    }

    const int tid  = threadIdx.x;
    const int wave = tid >> 6;
    const int lane = tid & 63;
    const int r15  = lane & 15;
    const int kq   = lane >> 4;
    const int kq8  = kq * 8;
    const int c_cl = (r15 < ncols) ? r15 : (ncols - 1);
    const bool cvalid = r15 < ncols;
    const int col  = c0 + c_cl;

    const float bi2 = bih[layer * 3 * D + 2 * D + col];
    const float bh2 = bhh[layer * 3 * D + 2 * D + col];
    const float bs0 = bih[layer * 3 * D + col] + bhh[layer * 3 * D + col];
    const float bs1 = bih[layer * 3 * D + D + col] + bhh[layer * 3 * D + D + col];

    const unsigned short* bp[6];
    #pragma unroll
    for (int mg = 0; mg < 6; ++mg) bp[mg] = wlds + (mg * ncols + c_cl) * ROWLEN;

    const int arow_off0 = (wave * 32 + r15) * D;
    const int arow_off1 = (wave * 32 + 16 + r15) * D;

    const int dil = 1 << layer;
    unsigned short* hist_l = hist + (size_t)layer * HSLOTS * BD;
    float* ringf_l = ring_f + (size_t)layer * 8 * BD;

    unsigned* pr0 = prog;
    unsigned* pr1 = prog + 128;
    unsigned* pr2 = prog + 256;
    unsigned* myflag = prog + layer * 128 + u;

    const int j2 = (lane < 21) ? lane + 64 : lane;   // lanes cover flags [0,85) x2

    for (int t = 0; t < TT; ++t) {
        // readiness only (no back-pressure: history is write-once; ring_f is same-WG)
        int th1, th2; unsigned *a1, *a2;
        if (layer == 0)      { a1 = pr0; th1 = t;     a2 = pr0; th2 = 0;     }
        else if (layer == 1) { a1 = pr0; th1 = t + 1; a2 = pr1; th2 = t - 1; }
        else                 { a1 = pr1; th1 = t + 1; a2 = pr2; th2 = t - 3; }

        if (wave == 0) {
            for (;;) {
                bool ok = true;
                if (th1 > 0) ok = ok && (int)AGLD(a1 + lane) >= th1 && (int)AGLD(a1 + j2) >= th1;
                if (th2 > 0) ok = ok && (int)AGLD(a2 + lane) >= th2 && (int)AGLD(a2 + j2) >= th2;
                if (__all(ok)) break;
                __builtin_amdgcn_s_sleep(1);
            }
            // NO acquire fence: every cross-WG address below is read for the
            // first time ever (write-once buffers) => no stale copy can exist.
        }
        __syncthreads();

        const unsigned short* hinb = layer ? hin_hist + (size_t)((layer - 1) * TT + t) * BD
                                           : xbf + (size_t)t * BD;
        const unsigned short* hprevb = hist_l + (size_t)(t - dil + 8) * BD;
        unsigned short*       houtb  = hist_l + (size_t)(t + 8) * BD;
        const float* hprevf = ringf_l + (size_t)((t - dil) & 7) * BD;
        float*       houtf  = ringf_l + (size_t)(t & 7) * BD;

        // ---- epilogue operand prefetch: hprevf via MALL-direct (ring reuse);
        // residual from write-once hinb via plain load.
        float hpv[8], rsv[8];
        #pragma unroll
        for (int rtl = 0; rtl < 2; ++rtl)
            #pragma unroll
            for (int q = 0; q < 4; ++q) {
                const int row = wave * 32 + rtl * 16 + kq * 4 + q;
                const size_t idx = (size_t)row * D + col;
                GLSCD(hpv[rtl * 4 + q], hprevf + idx);
                rsv[rtl * 4 + q] = bf2f(hinb[idx]);
            }
        SB;

        f32x4 acc[2][2][3] = {};
        bf16x8 A0[16], A1[16], A2[16];

#define ISSUE1(Av, KS, SL) { \
        Av[(SL) * 4 + 0] = *(const bf16x8*)(hinb   + arow_off0 + (KS) * 32 + kq8); \
        Av[(SL) * 4 + 1] = *(const bf16x8*)(hprevb + arow_off0 + (KS) * 32 + kq8); \
        Av[(SL) * 4 + 2] = *(const bf16x8*)(hinb   + arow_off1 + (KS) * 32 + kq8); \
        Av[(SL) * 4 + 3] = *(const bf16x8*)(hprevb + arow_off1 + (KS) * 32 + kq8); }
#define ISSUEG(Av, BASE) { ISSUE1(Av, (BASE) + 0, 0) ISSUE1(Av, (BASE) + 1, 1) \
                           ISSUE1(Av, (BASE) + 2, 2) ISSUE1(Av, (BASE) + 3, 3) \
                           SB; }
#define COMPG(Av, BASE) { _Pragma("unroll") for (int kk = 0; kk < 4; ++kk) { \
        bf16x8 Bv[6]; \
        _Pragma("unroll") for (int mg = 0; mg < 6; ++mg) \
            Bv[mg] = *(const bf16x8*)(bp[mg] + ((BASE) + kk) * 32 + kq8); \
        _Pragma("unroll") for (int g = 0; g < 3; ++g) { \
            acc[0][0][g] = __builtin_amdgcn_mfma_f32_16x16x32_bf16(Av[kk * 4 + 0], Bv[g],     acc[0][0][g], 0, 0, 0); \
            acc[0][1][g] = __builtin_amdgcn_mfma_f32_16x16x32_bf16(Av[kk * 4 + 1], Bv[3 + g], acc[0][1][g], 0, 0, 0); \
            acc[1][0][g] = __builtin_amdgcn_mfma_f32_16x16x32_bf16(Av[kk * 4 + 2], Bv[g],     acc[1][0][g], 0, 0, 0); \
            acc[1][1][g] = __builtin_amdgcn_mfma_f32_16x16x32_bf16(Av[kk * 4 + 3], Bv[3 + g], acc[1][1][g], 0, 0, 0); } } \
        SB; }

        ISSUEG(A0, 0);  ISSUEG(A1, 4);  ISSUEG(A2, 8);
        COMPG(A0, 0);   ISSUEG(A0, 12);
        COMPG(A1, 4);   ISSUEG(A1, 16);
        COMPG(A2, 8);   ISSUEG(A2, 20);
        COMPG(A0, 12);  ISSUEG(A0, 24);
        COMPG(A1, 16);  ISSUEG(A1, 28);
        COMPG(A2, 20);
        COMPG(A0, 24);
        COMPG(A1, 28);

        asm volatile("s_waitcnt vmcnt(0)");  // drain asm hpv loads
        SB;

        // ---- gates + residual; sc1 stores (MALL-level => remote first-touch
        // fills are fresh; ordered by drain+release+flag)
        #pragma unroll
        for (int rtl = 0; rtl < 2; ++rtl) {
            #pragma unroll
            for (int q = 0; q < 4; ++q) {
                const int row = wave * 32 + rtl * 16 + kq * 4 + q;
                const size_t idx = (size_t)row * D + col;
                float xr = acc[rtl][0][0][q] + acc[rtl][1][0][q] + bs0;
                float xz = acc[rtl][0][1][q] + acc[rtl][1][1][q] + bs1;
                float rg = 1.f / (1.f + __expf(-xr));
                float zg = 1.f / (1.f + __expf(-xz));
                float ng = tanhf(acc[rtl][0][2][q] + bi2 + rg * (acc[rtl][1][2][q] + bh2));
                float hp = hpv[rtl * 4 + q];
                float h  = (1.f - zg) * ng + zg * hp;
                float v = (h + rsv[rtl * 4 + q]) * 0.70710678f;
                float y = v > 0.f ? v : 0.2f * v;
                if (cvalid) {
                    AGST(&houtf[idx], h);
                    AGST(&houtb[idx], f2bf(h));
                    if (layer == 2) {
                        AGST(&out[(size_t)t * BD + idx], y);
                    } else {
                        AGST(&hin_hist[(size_t)(layer * TT + t) * BD + idx], f2bf(y));
                    }
                }
            }
        }

        asm volatile("s_waitcnt vmcnt(0)");
        __syncthreads();
        if (tid == 0) {
            __builtin_amdgcn_fence(__ATOMIC_RELEASE, "agent");
            AGST(myflag, (unsigned)(t + 1));
        }
    }
}

// ============================================================================
// Fallback (r12, proven): 8-ring + sc0sc1 MALL-direct reads, 8 waves/WG.
// Used only if ws_size can't hold the history buffers.
// ============================================================================
__global__ __launch_bounds__(512, 2) void dgru_mall(
    const unsigned short* __restrict__ xbf,
    const float* __restrict__ Wih, const float* __restrict__ Whh,
    const float* __restrict__ bih, const float* __restrict__ bhh,
    unsigned short* __restrict__ ring_bf, float* __restrict__ ring_f,
    unsigned short* __restrict__ hin_ring, float* __restrict__ out,
    unsigned* __restrict__ prog)
{
    __shared__ unsigned short wlds[78 * ROWLEN];
    const int grp = blockIdx.x & 7;
    const int p = 32 * grp + (blockIdx.x >> 3);
    if (p >= NUSED) return;
    const int layer = p / NWPL;
    const int u     = p % NWPL;
    const int ncols = (u < 4) ? 13 : 12;
    const int c0    = u * 12 + (u < 4 ? u : 4);
    const int tid = threadIdx.x;
    {
        const float* w0 = Wih + (size_t)layer * 3 * D * D;
        const float* w1 = Whh + (size_t)layer * 3 * D * D;
        const int nrows = 6 * ncols;
        const int rh = tid >> 8, t255 = tid & 255;
        for (int rid = rh; rid < nrows; rid += 2) {
            int m = rid / (3 * ncols);
            int rem = rid - m * 3 * ncols;
            int g = rem / ncols, c = rem - g * ncols;
            const float* src = (m ? w1 : w0) + ((size_t)g * D + c0 + c) * D + t255 * 4;
            float4 v = *(const float4*)src;
            ushort4 o = { f2bf(v.x), f2bf(v.y), f2bf(v.z), f2bf(v.w) };
            *(ushort4*)&wlds[rid * ROWLEN + t255 * 4] = o;
        }
        __syncthreads();
    }
    const int wave = tid >> 6, lane = tid & 63;
    const int r15 = lane & 15, kq = lane >> 4, kq8 = kq * 8;
    const int c_cl = (r15 < ncols) ? r15 : (ncols - 1);
    const bool cvalid = r15 < ncols;
    const int col = c0 + c_cl;
    const float bi2 = bih[layer * 3 * D + 2 * D + col];
    const float bh2 = bhh[layer * 3 * D + 2 * D + col];
    const float bs0 = bih[layer * 3 * D + col] + bhh[layer * 3 * D + col];
    const float bs1 = bih[layer * 3 * D + D + col] + bhh[layer * 3 * D + D + col];
    const unsigned short* bp[6];
    #pragma unroll
    for (int mg = 0; mg < 6; ++mg) bp[mg] = wlds + (mg * ncols + c_cl) * ROWLEN;
    const int arow_off = (wave * 16 + r15) * D + kq8;
    const int dil = 1 << layer;
    unsigned* pr0 = prog;
    unsigned* pr1 = prog + 128;
    unsigned* pr2 = prog + 256;
    unsigned* myflag = prog + layer * 128 + u;
    const int j2 = (lane < 21) ? lane + 64 : lane;

    for (int t = 0; t < TT; ++t) {
        int th1, th2, th3; unsigned *a1, *a2, *a3;
        if (layer == 0)      { a1 = pr0; th1 = t;     a2 = pr1; th2 = t - 7; a3 = pr2; th3 = 0;     }
        else if (layer == 1) { a1 = pr0; th1 = t + 1; a2 = pr1; th2 = t - 1; a3 = pr2; th3 = t - 7; }
        else                 { a1 = pr1; th1 = t + 1; a2 = pr2; th2 = t - 3; a3 = pr2; th3 = 0;     }
        if (wave == 0) {
            for (;;) {
                bool ok = true;
                if (th1 > 0) ok = ok && (int)AGLD(a1 + lane) >= th1 && (int)AGLD(a1 + j2) >= th1;
                if (th2 > 0) ok = ok && (int)AGLD(a2 + lane) >= th2 && (int)AGLD(a2 + j2) >= th2;
                if (th3 > 0) ok = ok && (int)AGLD(a3 + lane) >= th3 && (int)AGLD(a3 + j2) >= th3;
                if (__all(ok)) break;
                __builtin_amdgcn_s_sleep(1);
            }
        }
        __syncthreads();
        const unsigned short* hinb = layer ? hin_ring + (size_t)((layer - 1) * 8 + (t & 7)) * BD
                                           : xbf + (size_t)t * BD;
        const int rs = (t + 8 - dil) & 7, wsl = t & 7;
        const unsigned short* hprevb = ring_bf + (size_t)(layer * 8 + rs) * BD;
        const float* hprevf = ring_f + (size_t)(layer * 8 + rs) * BD;
        float* houtf = ring_f + (size_t)(layer * 8 + wsl) * BD;
        unsigned short* houtb = ring_bf + (size_t)(layer * 8 + wsl) * BD;
        const unsigned short* ba_h = hinb + arow_off;
        const unsigned short* ba_p = hprevb + arow_off;
        float hpv[4]; unsigned ru[4];
        #pragma unroll
        for (int q = 0; q < 4; ++q) {
            const int row = wave * 16 + kq * 4 + q;
            const size_t idx = (size_t)row * D + col;
            GLSCD(hpv[q], hprevf + idx);
            GLSCU(ru[q], hinb + idx);
        }
        SB;
        f32x4 acc[2][3] = {};
        bf16x8 A0[8], A1[8], A2[8], A3[8];
#define FISSUE1(Av, KS, SL) { \
        GLSC16(Av[(SL) * 2 + 0], ba_h, (KS) * 64); \
        GLSC16(Av[(SL) * 2 + 1], ba_p, (KS) * 64); }
#define FISSUEG(Av, BASE) { FISSUE1(Av, (BASE) + 0, 0) FISSUE1(Av, (BASE) + 1, 1) \
                            FISSUE1(Av, (BASE) + 2, 2) FISSUE1(Av, (BASE) + 3, 3) SB; }
#define FCOMPG(Av, BASE) { _Pragma("unroll") for (int kk = 0; kk < 4; ++kk) { \
        bf16x8 Bv[6]; \
        _Pragma("unroll") for (int mg = 0; mg < 6; ++mg) \
            Bv[mg] = *(const bf16x8*)(bp[mg] + ((BASE) + kk) * 32 + kq8); \
        _Pragma("unroll") for (int g = 0; g < 3; ++g) { \
            acc[0][g] = __builtin_amdgcn_mfma_f32_16x16x32_bf16(Av[kk * 2 + 0], Bv[g],     acc[0][g], 0, 0, 0); \
            acc[1][g] = __builtin_amdgcn_mfma_f32_16x16x32_bf16(Av[kk * 2 + 1], Bv[3 + g], acc[1][g], 0, 0, 0); } } \
        SB; }
        FISSUEG(A0, 0); FISSUEG(A1, 4); FISSUEG(A2, 8); FISSUEG(A3, 12);
        WAITV(24); FCOMPG(A0, 0);  FISSUEG(A0, 16);
        WAITV(24); FCOMPG(A1, 4);  FISSUEG(A1, 20);
        WAITV(24); FCOMPG(A2, 8);  FISSUEG(A2, 24);
        WAITV(24); FCOMPG(A3, 12); FISSUEG(A3, 28);
        WAITV(24); FCOMPG(A0, 16);
        WAITV(16); FCOMPG(A1, 20);
        WAITV(8);  FCOMPG(A2, 24);
        WAITV(0);  FCOMPG(A3, 28);
        #pragma unroll
        for (int q = 0; q < 4; ++q) {
            const int row = wave * 16 + kq * 4 + q;
            const size_t idx = (size_t)row * D + col;
            float xr = acc[0][0][q] + acc[1][0][q] + bs0;
            float xz = acc[0][1][q] + acc[1][1][q] + bs1;
            float rg = 1.f / (1.f + __expf(-xr));
            float zg = 1.f / (1.f + __expf(-xz));
            float ng = tanhf(acc[0][2][q] + bi2 + rg * (acc[1][2][q] + bh2));
            float h = (1.f - zg) * ng + zg * hpv[q];
            float v = (h + bf2f((unsigned short)ru[q])) * 0.70710678f;
            float y = v > 0.f ? v : 0.2f * v;
            if (cvalid) {
                AGST(&houtf[idx], h);
                AGST(&houtb[idx], f2bf(h));
                if (layer == 2) AGST(&out[(size_t)t * BD + idx], y);
                else            AGST(&hin_ring[(size_t)(layer * 8 + (t & 7)) * BD + idx], f2bf(y));
            }
        }
        asm volatile("s_waitcnt vmcnt(0)");
        __syncthreads();
        if (tid == 0) {
            __builtin_amdgcn_fence(__ATOMIC_RELEASE, "agent");
            AGST(myflag, (unsigned)(t + 1));
        }
    }
}

extern "C" void kernel_launch(void* const* d_in, const int* in_sizes, int n_in,
                              void* d_out, int out_size, void* d_ws, size_t ws_size,
                              hipStream_t stream) {
    const float* x   = (const float*)d_in[0];
    const float* Wih = (const float*)d_in[1];
    const float* Whh = (const float*)d_in[2];
    const float* bih = (const float*)d_in[3];
    const float* bhh = (const float*)d_in[4];
    float* out = (float*)d_out;

    char* ws = (char*)d_ws;
    size_t off = 0;
    auto alloc = [&](size_t bytes) -> void* {
        void* p = ws + off;
        off += (bytes + 255) & ~(size_t)255;
        return p;
    };

    const int NX = TT * BD;
    unsigned short* xbf = (unsigned short*)alloc((size_t)NX * 2);  // 67 MB

    // dedup-mode requirement: hist 207.7MB + ring_f 12.6MB + hin_hist 134.2MB
    const size_t NEED = ((size_t)NX * 2) + ((size_t)3 * HSLOTS * BD * 2)
                      + ((size_t)24 * BD * 4) + ((size_t)2 * TT * BD * 2) + 65536;

    if (ws_size >= NEED) {
        unsigned short* hist     = (unsigned short*)alloc((size_t)3 * HSLOTS * BD * 2);
        float*          ring_f   = (float*)alloc((size_t)24 * BD * 4);
        unsigned short* hin_hist = (unsigned short*)alloc((size_t)2 * TT * BD * 2);
        unsigned*       prog     = (unsigned*)alloc(2048);

        cvt_f32_bf16<<<NX / 8 / 256, 256, 0, stream>>>(x, xbf, NX);
        // zero: 8 pad slots per layer + ring_f + prog (history bodies are
        // always fully written before read)
        for (int l = 0; l < 3; ++l)
            hipMemsetAsync(hist + (size_t)l * HSLOTS * BD, 0, (size_t)8 * BD * 2, stream);
        hipMemsetAsync(ring_f, 0, (size_t)24 * BD * 4, stream);
        hipMemsetAsync(prog, 0, 2048, stream);

        dgru_dedup<<<NWG, 256, 0, stream>>>(
            xbf, Wih, Whh, bih, bhh, hist, ring_f, hin_hist, out, prog);
    } else {
        size_t zstart = off;
        unsigned short* ring_bf  = (unsigned short*)alloc((size_t)24 * BD * 2);
        float*          ring_f   = (float*)alloc((size_t)24 * BD * 4);
        unsigned short* hin_ring = (unsigned short*)alloc((size_t)16 * BD * 2);
        unsigned*       prog     = (unsigned*)alloc(2048);
        size_t zbytes = off - zstart;

        cvt_f32_bf16<<<NX / 8 / 256, 256, 0, stream>>>(x, xbf, NX);
        hipMemsetAsync(ws + zstart, 0, zbytes, stream);

        dgru_mall<<<NWG, 512, 0, stream>>>(
            xbf, Wih, Whh, bih, bhh, ring_bf, ring_f, hin_ring, out, prog);
    }
}